// Round 1
// baseline (189.982 us; speedup 1.0000x reference)
//
#include <hip/hip_runtime.h>
#include <math.h>

#define P   512
#define NA  180
#define NB  4

// ---------------------------------------------------------------------------
// Kernel 1: build the spatial-domain Shepp-Logan filter hr[512] and the
// sin/cos angle tables, all in double precision with exact integer phase
// (j*k mod 512) so the DFT matches numpy's FFT to ~1e-15.
// filtered = real(ifft(fft(s) * ff)) == circular_conv(s, Re(ifft(ff)))
// because s and ff are real.
// ---------------------------------------------------------------------------
__global__ __launch_bounds__(512) void ir_setup_kernel(float* __restrict__ hr,
                                                       float* __restrict__ sctab) {
    __shared__ double costab[P];
    __shared__ double ffs[P];
    const int t = threadIdx.x;  // 0..511

    costab[t] = cos((2.0 * M_PI / P) * (double)t);
    __syncthreads();

    // ff[t] = 2 * Re(FFT(f))[t], f even => FFT real.
    double acc = 0.25;  // f[0]
    #pragma unroll 4
    for (int m = 0; m < P / 2; ++m) {
        const int idx = 2 * m + 1;                  // odd indices 1..511
        const int n = (idx < P / 2) ? idx : (P - idx);
        const double fv = -1.0 / ((M_PI * n) * (M_PI * n));
        acc += fv * costab[(t * idx) & (P - 1)];
    }
    double ff = 2.0 * acc;
    if (t > 0) {
        // omega = pi * fftfreq(P)[t]; sinc factor is even so sign is irrelevant
        const double freq = (t <= P / 2) ? (double)t / P : (double)(t - P) / P;
        const double w = M_PI * freq;
        ff *= sin(w) / w;
    }
    ffs[t] = ff;
    __syncthreads();

    // hr[t] = Re(ifft(ff))[t] = (1/P) * sum_k ff[k] cos(2*pi*k*t/P)
    double hsum = 0.0;
    #pragma unroll 4
    for (int k = 0; k < P; ++k) hsum += ffs[k] * costab[(t * k) & (P - 1)];
    hr[t] = (float)(hsum / P);

    if (t < NA) {
        const double th = (double)t * M_PI / (double)(NA - 1);  // linspace(0,180,180) deg
        sctab[t] = (float)sin(th);
        sctab[NA + t] = (float)cos(th);
    }
}

// ---------------------------------------------------------------------------
// Kernel 2: circular convolution of each sinogram row with hr.
// One block per (b,a) row. filtered[n] = sum_k row[k] * hr[(n-k) mod 512].
// ---------------------------------------------------------------------------
__global__ __launch_bounds__(256) void ir_filter_kernel(const float* __restrict__ sino,
                                                        const float* __restrict__ hr,
                                                        float* __restrict__ filtered) {
    __shared__ float row[P];
    __shared__ float h2[2 * P];  // h2[i] = hr[i mod 512], two periods -> no mod in loop
    const int t = threadIdx.x;   // 0..255
    const float* src = sino + (size_t)blockIdx.x * P;
    row[t] = src[t];
    row[t + 256] = src[t + 256];
    const float hv0 = hr[t];
    const float hv1 = hr[t + 256];
    h2[t] = hv0;  h2[t + 256] = hv1;  h2[t + 512] = hv0;  h2[t + 768] = hv1;
    __syncthreads();

    const int n0 = t, n1 = t + 256;
    float a0 = 0.f, a1 = 0.f;
    #pragma unroll 8
    for (int k = 0; k < P; ++k) {
        const float rv = row[k];                 // broadcast (free)
        a0 = fmaf(rv, h2[P + n0 - k], a0);       // consecutive addrs across lanes
        a1 = fmaf(rv, h2[P + n1 - k], a1);
    }
    float* dst = filtered + (size_t)blockIdx.x * P;
    dst[n0] = a0;
    dst[n1] = a1;
}

// ---------------------------------------------------------------------------
// Kernel 3: backprojection. One thread per output pixel; block = 64x4 pixels.
// p = x*sin(th) + y*cos(th) + 256, bilinear with zero padding, sum over angles,
// scale by pi/(2*NA), circle mask.
// ---------------------------------------------------------------------------
__global__ __launch_bounds__(256) void ir_backproject_kernel(const float* __restrict__ filtered,
                                                             const float* __restrict__ sctab,
                                                             float* __restrict__ out) {
    __shared__ float s_sin[NA];
    __shared__ float s_cos[NA];
    const int t = threadIdx.x;
    if (t < NA) {
        s_sin[t] = sctab[t];
        s_cos[t] = sctab[NA + t];
    }
    __syncthreads();

    const int w = blockIdx.x * 64 + (t & 63);
    const int h = blockIdx.y * 4 + (t >> 6);
    const int b = blockIdx.z;

    const int ix = 255 - w;       // x[w] = (S-1-w) - S/2
    const int iy = h - 256;       // y[h] = h - S/2
    const float xf = (float)ix;
    const float yf = (float)iy;

    const float* base = filtered + (size_t)b * NA * P;

    float acc = 0.f;
    for (int a = 0; a < NA; ++a) {
        const float p = fmaf(xf, s_sin[a], fmaf(yf, s_cos[a], 256.0f));
        const float pf = floorf(p);
        const float frac = p - pf;
        const int i0 = (int)pf;
        const int i1 = i0 + 1;
        const float* rp = base + a * P;
        const int c0 = min(max(i0, 0), P - 1);
        const int c1 = min(max(i1, 0), P - 1);
        float v0 = rp[c0];
        float v1 = rp[c1];
        v0 = ((unsigned)i0 <= (unsigned)(P - 1)) ? v0 : 0.f;
        v1 = ((unsigned)i1 <= (unsigned)(P - 1)) ? v1 : 0.f;
        acc = fmaf(1.f - frac, v0, fmaf(frac, v1, acc));
    }

    const int mask = (ix * ix + iy * iy) <= (P / 2) * (P / 2);
    const float scale = (float)(M_PI / (2.0 * NA));
    out[((size_t)b * P + h) * P + w] = mask ? acc * scale : 0.f;
}

// ---------------------------------------------------------------------------
extern "C" void kernel_launch(void* const* d_in, const int* in_sizes, int n_in,
                              void* d_out, int out_size, void* d_ws, size_t ws_size,
                              hipStream_t stream) {
    const float* sino = (const float*)d_in[0];
    float* out = (float*)d_out;
    float* ws = (float*)d_ws;

    float* hr = ws;                     // 512 floats
    float* sctab = ws + 512;            // 360 floats
    float* filtered = ws + 1024;        // 4*180*512 = 368640 floats

    ir_setup_kernel<<<1, 512, 0, stream>>>(hr, sctab);
    ir_filter_kernel<<<NB * NA, 256, 0, stream>>>(sino, hr, filtered);

    dim3 grid(P / 64, P / 4, NB);
    ir_backproject_kernel<<<grid, 256, 0, stream>>>(filtered, sctab, out);
}

// Round 2
// 166.248 us; speedup vs baseline: 1.1428x; 1.1428x over previous
//
#include <hip/hip_runtime.h>
#include <math.h>

#define P        512
#define NA       180
#define NB       4
#define FSTRIDE  528   // padded row: [0..7]=0, [8..519]=data, [520..527]=0
#define FOFF     8

// ---------------------------------------------------------------------------
// setup A (1 block, 512 thr): cos table (double cos -> f32), sinc-weighted
// ff spectrum (fp32, incremental integer phase), angle sin/cos pairs.
//   ff[t] = 2*(0.25 + sum_m fodd[m]*cos(2*pi*t*(2m+1)/P)) * sinc(pi*fftfreq[t])
// ---------------------------------------------------------------------------
__global__ __launch_bounds__(512) void ir_setup_a(float* __restrict__ ffg,
                                                  float* __restrict__ ctg,
                                                  float* __restrict__ sctab2) {
    __shared__ float costab[P];
    __shared__ float fodd[P / 2];
    const int t = threadIdx.x;  // 0..511

    const double ang = (2.0 * M_PI / P) * (double)t;
    const float ct = (float)cos(ang);
    costab[t] = ct;
    ctg[t] = ct;
    if (t < P / 2) {
        const int idx = 2 * t + 1;
        const int n = (idx < P / 2) ? idx : (P - idx);
        const double w = M_PI * (double)n;
        fodd[t] = (float)(-1.0 / (w * w));   // one f64 div per thread, total 256
    }
    if (t < NA) {
        const double th = (double)t * (M_PI / (double)(NA - 1));  // linspace incl. endpoint
        sctab2[2 * t] = (float)sin(th);
        sctab2[2 * t + 1] = (float)cos(th);
    }
    __syncthreads();

    float acc = 0.25f;
    int phase = t;                       // t*(2m+1) mod P, m=0
    const int step = (2 * t) & (P - 1);
    #pragma unroll 4
    for (int m = 0; m < P / 2; ++m) {
        acc = fmaf(fodd[m], costab[phase], acc);
        phase = (phase + step) & (P - 1);
    }
    float ff = 2.0f * acc;
    if (t > 0) {
        const double freq = (t <= P / 2) ? (double)t / P : ((double)t - P) / P;
        const double w = M_PI * freq;    // sinc is even; sign irrelevant
        ff = (float)((double)ff * (sin(w) / w));
    }
    ffg[t] = ff;
}

// ---------------------------------------------------------------------------
// setup B (512 blocks, 64 thr): hr[o] = (1/P) sum_k ff[k] cos(2*pi*k*o/P)
// ---------------------------------------------------------------------------
__global__ __launch_bounds__(64) void ir_setup_b(const float* __restrict__ ffg,
                                                 const float* __restrict__ ctg,
                                                 float* __restrict__ hr) {
    const int o = blockIdx.x;   // 0..511
    const int t = threadIdx.x;  // 0..63
    float s = 0.f;
    #pragma unroll
    for (int i = 0; i < 8; ++i) {
        const int k = t + 64 * i;
        s = fmaf(ffg[k], ctg[(o * k) & (P - 1)], s);
    }
    #pragma unroll
    for (int off = 32; off; off >>= 1) s += __shfl_down(s, off, 64);
    if (t == 0) hr[o] = s * (1.0f / P);
}

// ---------------------------------------------------------------------------
// filter: filtered[n] = sum_j hr[j] * row[(n-j) mod 512]
// 2 rows/block, 4 outputs/thread, h via wave-uniform (scalar) loads,
// row taps via ds_read_b128 sliding window. Writes zero pads.
// ---------------------------------------------------------------------------
__global__ __launch_bounds__(256) void ir_filter_kernel(const float* __restrict__ sino,
                                                        const float* __restrict__ hr,
                                                        float* __restrict__ filtered) {
    __shared__ float row2[2][2 * P];   // row2[r][i] = row[i & 511], i in [0,1024)
    const int t = threadIdx.x;
    const int r = t >> 7;              // row within block
    const int tt = t & 127;            // 0..127, outputs 4tt..4tt+3
    const int rowIdx = blockIdx.x * 2 + r;

    const float* src = sino + (size_t)rowIdx * P;
    const float4 v = *(const float4*)(src + 4 * tt);
    *(float4*)&row2[r][4 * tt] = v;
    *(float4*)&row2[r][4 * tt + P] = v;
    __syncthreads();

    float a0 = 0.f, a1 = 0.f, a2 = 0.f, a3 = 0.f;
    #pragma unroll 2
    for (int J = 0; J < P; J += 4) {
        const int base = P + 4 * tt - J;                    // multiple of 4
        const float4 A = *(const float4*)&row2[r][base];     // w[0..3]
        const float4 Bv = *(const float4*)&row2[r][base - 4]; // w[-4..-1]
        const float h0 = hr[J], h1 = hr[J + 1], h2v = hr[J + 2], h3 = hr[J + 3];
        // out[c] += sum_dj h[J+dj] * w[c-dj]
        a0 = fmaf(h0, A.x, a0); a0 = fmaf(h1, Bv.w, a0); a0 = fmaf(h2v, Bv.z, a0); a0 = fmaf(h3, Bv.y, a0);
        a1 = fmaf(h0, A.y, a1); a1 = fmaf(h1, A.x, a1); a1 = fmaf(h2v, Bv.w, a1); a1 = fmaf(h3, Bv.z, a1);
        a2 = fmaf(h0, A.z, a2); a2 = fmaf(h1, A.y, a2); a2 = fmaf(h2v, A.x, a2); a2 = fmaf(h3, Bv.w, a2);
        a3 = fmaf(h0, A.w, a3); a3 = fmaf(h1, A.z, a3); a3 = fmaf(h2v, A.y, a3); a3 = fmaf(h3, A.x, a3);
    }
    float* dst = filtered + (size_t)rowIdx * FSTRIDE;
    *(float4*)(dst + FOFF + 4 * tt) = make_float4(a0, a1, a2, a3);
    if (tt < FOFF) {                    // zero pads (ws is poisoned every call)
        dst[tt] = 0.f;
        dst[FOFF + P + tt] = 0.f;
    }
}

// ---------------------------------------------------------------------------
// backprojection: 2 pixels per thread (rows h and h+256 share x*sin fma).
// pp = p + 1 (bias folded into constant 257) -> tap indices >= 0, padded rows
// make all taps branch/clamp/select-free. sin/cos via scalar loads.
// ---------------------------------------------------------------------------
__global__ __launch_bounds__(256) void ir_backproject_kernel(const float* __restrict__ filtered,
                                                             const float* __restrict__ sctab2,
                                                             float* __restrict__ out) {
    const int t = threadIdx.x;
    const int w = blockIdx.x * 64 + (t & 63);
    const int h = blockIdx.y * 4 + (t >> 6);   // 0..255; second pixel at h+256
    const int b = blockIdx.z;

    const int ix = 255 - w;                    // x (reversed axis)
    const int iy = h - 256;                    // y for pixel 1; pixel 2: iy+256
    const float xf = (float)ix;
    const float yf = (float)iy;

    // rp[idx] with idx = floor(p)+1 must hit data element floor(p):
    // data element k lives at rowbase[FOFF + k] -> rp = rowbase + FOFF - 1
    const float* fb = filtered + (size_t)b * NA * FSTRIDE + (FOFF - 1);

    float acc1 = 0.f, acc2 = 0.f;
    #pragma unroll 4
    for (int a = 0; a < NA; ++a) {
        const float sv = sctab2[2 * a];        // wave-uniform -> s_load
        const float cv = sctab2[2 * a + 1];
        float pp1 = fmaf(yf, cv, 257.0f);      // p + 1
        pp1 = fmaf(xf, sv, pp1);
        const float pp2 = fmaf(256.0f, cv, pp1);  // pixel at y+256
        const float* rp = fb + a * FSTRIDE;
        {
            const float pc = fminf(fmaxf(pp1, 0.0f), 514.0f);
            const float pf = floorf(pc);
            const float fr = pc - pf;
            const int idx = (int)pf;           // 0..514
            const float v0 = rp[idx];
            const float v1 = rp[idx + 1];
            acc1 = fmaf(1.0f - fr, v0, fmaf(fr, v1, acc1));
        }
        {
            const float pc = fminf(fmaxf(pp2, 0.0f), 514.0f);
            const float pf = floorf(pc);
            const float fr = pc - pf;
            const int idx = (int)pf;
            const float v0 = rp[idx];
            const float v1 = rp[idx + 1];
            acc2 = fmaf(1.0f - fr, v0, fmaf(fr, v1, acc2));
        }
    }

    const float scale = (float)(M_PI / (2.0 * NA));
    const int r2 = (P / 2) * (P / 2);
    const int iy2 = iy + 256;
    const int m1 = (ix * ix + iy * iy) <= r2;
    const int m2 = (ix * ix + iy2 * iy2) <= r2;
    float* o1 = out + ((size_t)b * P + h) * P + w;
    o1[0] = m1 ? acc1 * scale : 0.f;
    o1[256 * P] = m2 ? acc2 * scale : 0.f;
}

// ---------------------------------------------------------------------------
extern "C" void kernel_launch(void* const* d_in, const int* in_sizes, int n_in,
                              void* d_out, int out_size, void* d_ws, size_t ws_size,
                              hipStream_t stream) {
    const float* sino = (const float*)d_in[0];
    float* out = (float*)d_out;
    float* ws = (float*)d_ws;

    float* hr = ws;                 // 512
    float* sctab2 = ws + 512;       // 360
    float* ffg = ws + 896;          // 512
    float* ctg = ws + 1408;         // 512
    float* filtered = ws + 1920;    // 720 * 528 = 380160 floats (~1.53 MB total)

    ir_setup_a<<<1, 512, 0, stream>>>(ffg, ctg, sctab2);
    ir_setup_b<<<P, 64, 0, stream>>>(ffg, ctg, hr);
    ir_filter_kernel<<<NB * NA / 2, 256, 0, stream>>>(sino, hr, filtered);

    dim3 grid(P / 64, 256 / 4, NB);
    ir_backproject_kernel<<<grid, 256, 0, stream>>>(filtered, sctab2, out);
}

// Round 3
// 163.061 us; speedup vs baseline: 1.1651x; 1.0195x over previous
//
#include <hip/hip_runtime.h>
#include <math.h>

#define P        512
#define NA       180
#define NB       4
#define FSTRIDE  528   // padded row: [0..7]=0, [8..519]=data, [520..527]=0
#define FOFF     8

#if __has_builtin(__builtin_amdgcn_fractf)
#define FRACT(x) __builtin_amdgcn_fractf(x)
#else
#define FRACT(x) ((x) - floorf(x))
#endif

typedef float v2f __attribute__((ext_vector_type(2), aligned(4)));

// ---------------------------------------------------------------------------
// K1 (8 blocks x 64): all f64 transcendentals, spread across CUs.
// ---------------------------------------------------------------------------
__global__ __launch_bounds__(64) void ir_setup_tables(float* __restrict__ ctg,
                                                      float* __restrict__ fodd,
                                                      float* __restrict__ sincg,
                                                      float* __restrict__ sctab2) {
    const int t = blockIdx.x * 64 + threadIdx.x;  // 0..511
    ctg[t] = (float)cos((2.0 * M_PI / P) * (double)t);
    if (t < P / 2) {
        const int idx = 2 * t + 1;
        const int n = (idx < P / 2) ? idx : (P - idx);
        const double w = M_PI * (double)n;
        fodd[t] = (float)(-1.0 / (w * w));
    }
    double sc = 1.0;
    if (t > 0) {
        const double freq = (t <= P / 2) ? (double)t / P : ((double)t - P) / P;
        const double w = M_PI * freq;   // sinc is even; fftfreq sign irrelevant
        sc = sin(w) / w;
    }
    sincg[t] = (float)sc;
    if (t < NA) {
        const double th = (double)t * (M_PI / (double)(NA - 1));  // linspace incl endpoint
        sctab2[2 * t] = (float)sin(th);
        sctab2[2 * t + 1] = (float)cos(th);
    }
}

// ---------------------------------------------------------------------------
// K2 (512 blocks x 64): ff[o] = 2*(0.25 + sum_m fodd[m] cos(2pi o(2m+1)/P)) * sinc[o]
// ---------------------------------------------------------------------------
__global__ __launch_bounds__(64) void ir_spectrum(const float* __restrict__ ctg,
                                                  const float* __restrict__ fodd,
                                                  const float* __restrict__ sincg,
                                                  float* __restrict__ ffg) {
    const int o = blockIdx.x;
    const int t = threadIdx.x;
    float s = 0.f;
    #pragma unroll
    for (int i = 0; i < 4; ++i) {
        const int m = t + 64 * i;
        s = fmaf(fodd[m], ctg[(o * (2 * m + 1)) & (P - 1)], s);
    }
    #pragma unroll
    for (int off = 32; off; off >>= 1) s += __shfl_down(s, off, 64);
    if (t == 0) ffg[o] = fmaf(2.f, s, 0.5f) * sincg[o];
}

// ---------------------------------------------------------------------------
// K3 (512 blocks x 64): hr[o] = (1/P) sum_k ff[k] cos(2pi k o / P)
// ---------------------------------------------------------------------------
__global__ __launch_bounds__(64) void ir_setup_b(const float* __restrict__ ffg,
                                                 const float* __restrict__ ctg,
                                                 float* __restrict__ hr) {
    const int o = blockIdx.x;
    const int t = threadIdx.x;
    float s = 0.f;
    #pragma unroll
    for (int i = 0; i < 8; ++i) {
        const int k = t + 64 * i;
        s = fmaf(ffg[k], ctg[(o * k) & (P - 1)], s);
    }
    #pragma unroll
    for (int off = 32; off; off >>= 1) s += __shfl_down(s, off, 64);
    if (t == 0) hr[o] = s * (1.0f / P);
}

// ---------------------------------------------------------------------------
// filter: filtered[n] = sum_j hr[j] * row[(n-j) mod 512]  (unchanged, verified)
// ---------------------------------------------------------------------------
__global__ __launch_bounds__(256) void ir_filter_kernel(const float* __restrict__ sino,
                                                        const float* __restrict__ hr,
                                                        float* __restrict__ filtered) {
    __shared__ float row2[2][2 * P];
    const int t = threadIdx.x;
    const int r = t >> 7;
    const int tt = t & 127;
    const int rowIdx = blockIdx.x * 2 + r;

    const float* src = sino + (size_t)rowIdx * P;
    const float4 v = *(const float4*)(src + 4 * tt);
    *(float4*)&row2[r][4 * tt] = v;
    *(float4*)&row2[r][4 * tt + P] = v;
    __syncthreads();

    float a0 = 0.f, a1 = 0.f, a2 = 0.f, a3 = 0.f;
    #pragma unroll 2
    for (int J = 0; J < P; J += 4) {
        const int base = P + 4 * tt - J;
        const float4 A = *(const float4*)&row2[r][base];
        const float4 Bv = *(const float4*)&row2[r][base - 4];
        const float h0 = hr[J], h1 = hr[J + 1], h2v = hr[J + 2], h3 = hr[J + 3];
        a0 = fmaf(h0, A.x, a0); a0 = fmaf(h1, Bv.w, a0); a0 = fmaf(h2v, Bv.z, a0); a0 = fmaf(h3, Bv.y, a0);
        a1 = fmaf(h0, A.y, a1); a1 = fmaf(h1, A.x, a1); a1 = fmaf(h2v, Bv.w, a1); a1 = fmaf(h3, Bv.z, a1);
        a2 = fmaf(h0, A.z, a2); a2 = fmaf(h1, A.y, a2); a2 = fmaf(h2v, A.x, a2); a2 = fmaf(h3, Bv.w, a2);
        a3 = fmaf(h0, A.w, a3); a3 = fmaf(h1, A.z, a3); a3 = fmaf(h2v, A.y, a3); a3 = fmaf(h3, A.x, a3);
    }
    float* dst = filtered + (size_t)rowIdx * FSTRIDE;
    *(float4*)(dst + FOFF + 4 * tt) = make_float4(a0, a1, a2, a3);
    if (tt < FOFF) {
        dst[tt] = 0.f;
        dst[FOFF + P + tt] = 0.f;
    }
}

// ---------------------------------------------------------------------------
// backprojection: 8x8 pixel tile per wave (gather span <= 2 cache lines at any
// angle), 2 pixels/thread (y and y+256), one unaligned float2 gather per tap
// pair, fract + trunc indexing, no clamps (idx&1023 + ws slack absorbs
// out-of-circle overshoot), block-level circle-skip vote.
// ---------------------------------------------------------------------------
__global__ __launch_bounds__(256) void ir_backproject_kernel(const float* __restrict__ filtered,
                                                             const float* __restrict__ sctab2,
                                                             float* __restrict__ out) {
    const int t = threadIdx.x;
    const int lane = t & 63;
    const int wave = t >> 6;                       // 0..3 -> 2x2 waves of 8x8
    const int w = blockIdx.x * 16 + (wave & 1) * 8 + (lane & 7);
    const int h = blockIdx.y * 16 + (wave >> 1) * 8 + (lane >> 3);  // 0..255
    const int b = blockIdx.z;

    const int ix = 255 - w;                        // reversed x axis
    const int iy = h - 256;
    const int iy2 = iy + 256;
    const int r2 = 256 * 256;
    const int m1 = (ix * ix + iy * iy) <= r2;
    const int m2 = (ix * ix + iy2 * iy2) <= r2;

    float* o1 = out + ((size_t)b * P + h) * P + w;

    if (__syncthreads_count(m1 | m2) == 0) {       // whole block outside circle
        o1[0] = 0.f;
        o1[256 * P] = 0.f;
        return;
    }

    const float xf = (float)ix;
    const float yf = (float)iy;
    // rp[idx] (idx = floor(p)+1) must read (data[floor(p)], data[floor(p)+1]):
    // data[k] at rowbase[FOFF+k] -> rp = rowbase + FOFF - 1
    const float* fb = filtered + (size_t)b * (NA * FSTRIDE) + (FOFF - 1);

    float acc1 = 0.f, acc2 = 0.f;
    #pragma unroll 4
    for (int a = 0; a < NA; ++a) {
        const float sv = sctab2[2 * a];            // wave-uniform -> scalar loads
        const float cv = sctab2[2 * a + 1];
        const float q1 = fmaf(xf, sv, fmaf(yf, cv, 257.0f));   // p + 1
        const float q2 = fmaf(256.0f, cv, q1);                 // pixel at y+256
        const float* rp = fb + a * FSTRIDE;
        {
            const int idx = ((int)q1) & 1023;      // in-circle: q1>=1 -> trunc==floor
            const float fr = FRACT(q1);
            const v2f pr = *(const v2f*)(rp + idx);
            acc1 = fmaf(1.0f - fr, pr.x, fmaf(fr, pr.y, acc1));
        }
        {
            const int idx = ((int)q2) & 1023;
            const float fr = FRACT(q2);
            const v2f pr = *(const v2f*)(rp + idx);
            acc2 = fmaf(1.0f - fr, pr.x, fmaf(fr, pr.y, acc2));
        }
    }

    const float scale = (float)(M_PI / (2.0 * NA));
    o1[0] = m1 ? acc1 * scale : 0.f;
    o1[256 * P] = m2 ? acc2 * scale : 0.f;
}

// ---------------------------------------------------------------------------
extern "C" void kernel_launch(void* const* d_in, const int* in_sizes, int n_in,
                              void* d_out, int out_size, void* d_ws, size_t ws_size,
                              hipStream_t stream) {
    const float* sino = (const float*)d_in[0];
    float* out = (float*)d_out;
    float* ws = (float*)d_ws;

    float* ctg      = ws;            // 512
    float* fodd     = ws + 512;      // 256
    float* sincg    = ws + 768;      // 512
    float* sctab2   = ws + 1280;     // 360
    float* ffg      = ws + 1664;     // 512
    float* hr       = ws + 2176;     // 512
    float* filtered = ws + 2688;     // 720*528 = 380160 (+1024 slack for &1023 overshoot)

    ir_setup_tables<<<8, 64, 0, stream>>>(ctg, fodd, sincg, sctab2);
    ir_spectrum<<<P, 64, 0, stream>>>(ctg, fodd, sincg, ffg);
    ir_setup_b<<<P, 64, 0, stream>>>(ffg, ctg, hr);
    ir_filter_kernel<<<NB * NA / 2, 256, 0, stream>>>(sino, hr, filtered);

    dim3 grid(P / 16, 256 / 16, NB);
    ir_backproject_kernel<<<grid, 256, 0, stream>>>(filtered, sctab2, out);
}

// Round 4
// 154.999 us; speedup vs baseline: 1.2257x; 1.0520x over previous
//
#include <hip/hip_runtime.h>
#include <math.h>

#define P        512
#define NA       180
#define NB       4
#define FSTRIDE  528   // padded filtered row: [0..7]=0, [8..519]=data, [520..527]=0
#define FOFF     8
#define GUARD    128   // float guard before/after `filtered` in ws for window overreach
#define TS       32    // backprojection pixel tile
#define WS       50    // window floats per angle (span <= 46 used, +slack)

#if __has_builtin(__builtin_amdgcn_fractf)
#define FRACT(x) __builtin_amdgcn_fractf(x)
#else
#define FRACT(x) ((x) - floorf(x))
#endif

typedef float v2f __attribute__((ext_vector_type(2), aligned(4)));

// ---------------------------------------------------------------------------
// K1: fused filter. Each block (2 sinogram rows) rebuilds the Shepp-Logan
// spatial filter hr[512] in LDS (cos table + ff spectrum + inverse DFT; same
// verified math as rounds 1-3), then circular-convolves its rows.
// filtered[n] = sum_j hr[j] * row[(n-j) mod 512]
// ---------------------------------------------------------------------------
__global__ __launch_bounds__(256) void ir_filter_fused(const float* __restrict__ sino,
                                                       float* __restrict__ filtered) {
    __shared__ float costab[P];
    __shared__ float fodd[P / 2];
    __shared__ float ffs[P];
    __shared__ float hrs[P];
    __shared__ float row2[2][2 * P];
    const int t = threadIdx.x;
    const int r = t >> 7;             // row within block
    const int tt = t & 127;           // 0..127, outputs 4tt..4tt+3
    const int rowIdx = blockIdx.x * 2 + r;

    // stage sinogram rows (independent of table build)
    const float* src = sino + (size_t)rowIdx * P;
    const float4 v = *(const float4*)(src + 4 * tt);
    *(float4*)&row2[r][4 * tt] = v;
    *(float4*)&row2[r][4 * tt + P] = v;

    // tables
    costab[t]       = (float)cos((2.0 * M_PI / P) * (double)t);
    costab[t + 256] = (float)cos((2.0 * M_PI / P) * (double)(t + 256));
    if (t < P / 2) {
        const int idx = 2 * t + 1;
        const int n = (idx < P / 2) ? idx : (P - idx);
        const double w = M_PI * (double)n;
        fodd[t] = (float)(-1.0 / (w * w));
    }
    __syncthreads();

    // ff[o] = 2*(0.25 + sum_m fodd[m] cos(2pi o(2m+1)/P)) * sinc(pi*fftfreq[o])
    #pragma unroll
    for (int e = 0; e < 2; ++e) {
        const int o = t + 256 * e;
        float acc = 0.25f;
        int phase = o & (P - 1);
        const int step = (2 * o) & (P - 1);
        #pragma unroll 4
        for (int m = 0; m < P / 2; ++m) {
            acc = fmaf(fodd[m], costab[phase], acc);
            phase = (phase + step) & (P - 1);
        }
        float ff = 2.0f * acc;
        if (o > 0) {
            const double freq = (o <= P / 2) ? (double)o / P : ((double)o - P) / P;
            const double w = M_PI * freq;   // sinc even; fftfreq sign irrelevant
            ff = (float)((double)ff * (sin(w) / w));
        }
        ffs[o] = ff;
    }
    __syncthreads();

    // hr[o] = (1/P) sum_k ff[k] cos(2pi k o / P)
    #pragma unroll
    for (int e = 0; e < 2; ++e) {
        const int o = t + 256 * e;
        float s = 0.f;
        int phase = 0;
        const int step = o & (P - 1);
        #pragma unroll 4
        for (int k = 0; k < P; ++k) {
            s = fmaf(ffs[k], costab[phase], s);
            phase = (phase + step) & (P - 1);
        }
        hrs[o] = s * (1.0f / P);
    }
    __syncthreads();

    // circular convolution (verified structure from rounds 2-3)
    float a0 = 0.f, a1 = 0.f, a2 = 0.f, a3 = 0.f;
    #pragma unroll 2
    for (int J = 0; J < P; J += 4) {
        const int base = P + 4 * tt - J;
        const float4 A  = *(const float4*)&row2[r][base];
        const float4 Bv = *(const float4*)&row2[r][base - 4];
        const float h0 = hrs[J], h1 = hrs[J + 1], h2v = hrs[J + 2], h3 = hrs[J + 3];
        a0 = fmaf(h0, A.x, a0); a0 = fmaf(h1, Bv.w, a0); a0 = fmaf(h2v, Bv.z, a0); a0 = fmaf(h3, Bv.y, a0);
        a1 = fmaf(h0, A.y, a1); a1 = fmaf(h1, A.x, a1); a1 = fmaf(h2v, Bv.w, a1); a1 = fmaf(h3, Bv.z, a1);
        a2 = fmaf(h0, A.z, a2); a2 = fmaf(h1, A.y, a2); a2 = fmaf(h2v, A.x, a2); a2 = fmaf(h3, Bv.w, a2);
        a3 = fmaf(h0, A.w, a3); a3 = fmaf(h1, A.z, a3); a3 = fmaf(h2v, A.y, a3); a3 = fmaf(h3, A.x, a3);
    }
    float* dst = filtered + (size_t)rowIdx * FSTRIDE;
    *(float4*)(dst + FOFF + 4 * tt) = make_float4(a0, a1, a2, a3);
    if (tt < FOFF) {               // zero pads (ws re-poisoned every call)
        dst[tt] = 0.f;
        dst[FOFF + P + tt] = 0.f;
    }
}

// ---------------------------------------------------------------------------
// K2: backprojection via per-tile LDS windows.
// Block = 32x32 pixel tile for one batch (grid.z). Since p = x*s + y*c + 256
// is linear in (w,h), the tile's p-range is bounded by its corners (span <=
// 31*sqrt(2) ~ 43.9), so a 50-float window per angle covers every tap of
// every pixel in the tile -- clamp-free, branch-free LDS bilinear reads.
// ---------------------------------------------------------------------------
__global__ __launch_bounds__(256) void ir_backproject_kernel(const float* __restrict__ filtered,
                                                             float* __restrict__ out) {
    __shared__ float4 angc[NA];    // (s, c, fb = 256 - base, (float)base)
    __shared__ float win[NA * WS];

    const int t = threadIdx.x;
    const int lane = t & 63;
    const int wave = t >> 6;
    const int w0 = blockIdx.x * TS, h0 = blockIdx.y * TS;
    const int b = blockIdx.z;

    // thread's 4 pixels: (w,h), (w+16,h), (w,h+16), (w+16,h+16)
    const int w = w0 + (lane & 15);
    const int h = h0 + (lane >> 4) + 4 * wave;

    const int ix0 = 255 - w, ix1 = ix0 - 16;   // reversed x axis
    const int iy0 = h - 256, iy1 = iy0 + 16;
    const int r2 = 256 * 256;
    const int m00 = (ix0 * ix0 + iy0 * iy0) <= r2;
    const int m01 = (ix1 * ix1 + iy0 * iy0) <= r2;
    const int m10 = (ix0 * ix0 + iy1 * iy1) <= r2;
    const int m11 = (ix1 * ix1 + iy1 * iy1) <= r2;

    float* o0 = out + (((size_t)b * P) + h) * P + w;

    if (__syncthreads_count(m00 | m01 | m10 | m11) == 0) {  // tile fully outside circle
        o0[0] = 0.f; o0[16] = 0.f; o0[16 * P] = 0.f; o0[16 * P + 16] = 0.f;
        return;
    }

    // Phase A: per-angle constants (sin/cos + window base from tile corners)
    if (t < NA) {
        const float th = (float)t * (float)(M_PI / (double)(NA - 1));
        const float s = sinf(th), c = cosf(th);
        const float xlo = (float)(224 - w0);              // min x over tile (s >= 0)
        const float ylo = (float)(h0 - 256), yhi = (float)(h0 - 225);
        const float pmin = s * xlo + fminf(c * ylo, c * yhi) + 256.0f;
        const int base = (int)floorf(pmin) - 1;           // -1: fp-slop safety
        angc[t] = make_float4(s, c, (float)(256 - base), (float)base);
    }
    __syncthreads();

    // Phase B: stage 180 windows of this batch's filtered rows into LDS
    const float* fbatch = filtered + (size_t)b * NA * FSTRIDE + FOFF;
    for (int idx = t; idx < NA * (WS / 2); idx += 256) {
        const int a = idx / (WS / 2);
        const int i = idx - a * (WS / 2);
        const int base = (int)angc[a].w;
        const v2f vv = *(const v2f*)(fbatch + a * FSTRIDE + base + 2 * i);
        *(v2f*)(win + a * WS + 2 * i) = vv;               // a*WS even -> 8B aligned
    }
    __syncthreads();

    // Phase C: accumulate. q = p - base >= ~1; j = trunc(q), fr = fract(q).
    const float xf = (float)ix0;
    const float yf = (float)iy0;
    float acc00 = 0.f, acc01 = 0.f, acc10 = 0.f, acc11 = 0.f;
    #pragma unroll 2
    for (int a = 0; a < NA; ++a) {
        const float4 ac = angc[a];
        const float q00 = fmaf(xf, ac.x, fmaf(yf, ac.y, ac.z));
        const float q01 = fmaf(-16.f, ac.x, q00);         // w+16 -> x-16
        const float q10 = fmaf( 16.f, ac.y, q00);         // h+16 -> y+16
        const float q11 = fmaf( 16.f, ac.y, q01);
        const float* wb = win + a * WS;
        {
            const int j = (int)q00; const float fr = FRACT(q00);
            const v2f pv = *(const v2f*)(wb + j);
            acc00 = fmaf(1.f - fr, pv.x, fmaf(fr, pv.y, acc00));
        }
        {
            const int j = (int)q01; const float fr = FRACT(q01);
            const v2f pv = *(const v2f*)(wb + j);
            acc01 = fmaf(1.f - fr, pv.x, fmaf(fr, pv.y, acc01));
        }
        {
            const int j = (int)q10; const float fr = FRACT(q10);
            const v2f pv = *(const v2f*)(wb + j);
            acc10 = fmaf(1.f - fr, pv.x, fmaf(fr, pv.y, acc10));
        }
        {
            const int j = (int)q11; const float fr = FRACT(q11);
            const v2f pv = *(const v2f*)(wb + j);
            acc11 = fmaf(1.f - fr, pv.x, fmaf(fr, pv.y, acc11));
        }
    }

    const float scale = (float)(M_PI / (2.0 * NA));
    o0[0]          = m00 ? acc00 * scale : 0.f;
    o0[16]         = m01 ? acc01 * scale : 0.f;
    o0[16 * P]     = m10 ? acc10 * scale : 0.f;
    o0[16 * P + 16] = m11 ? acc11 * scale : 0.f;
}

// ---------------------------------------------------------------------------
extern "C" void kernel_launch(void* const* d_in, const int* in_sizes, int n_in,
                              void* d_out, int out_size, void* d_ws, size_t ws_size,
                              hipStream_t stream) {
    const float* sino = (const float*)d_in[0];
    float* out = (float*)d_out;
    float* ws = (float*)d_ws;

    // filtered sits GUARD floats in; window staging may overreach ~100 floats
    // front (first rows) / ~85 floats back (last row) -- both land in ws.
    float* filtered = ws + GUARD;      // 720*528 = 380160 floats

    ir_filter_fused<<<NB * NA / 2, 256, 0, stream>>>(sino, filtered);

    dim3 grid(P / TS, P / TS, NB);
    ir_backproject_kernel<<<grid, 256, 0, stream>>>(filtered, out);
}

// Round 5
// 121.154 us; speedup vs baseline: 1.5681x; 1.2794x over previous
//
#include <hip/hip_runtime.h>
#include <math.h>

#define P      512
#define NA     180
#define NB     4
#define FS2    1056    // interleaved pair row: 16 zero + 1024 data + 16 zero floats
#define FOFF2  16
#define GUARD  512     // float guard before/after fil2 for window-staging overreach
#define TS     32      // backprojection pixel tile
#define WSF    100     // window floats per angle (50 positions x 2 batches)

#if __has_builtin(__builtin_amdgcn_fractf)
#define FRACT(x) __builtin_amdgcn_fractf(x)
#else
#define FRACT(x) ((x) - floorf(x))
#endif

typedef float f4g __attribute__((ext_vector_type(4), aligned(16)));
typedef float f4l __attribute__((ext_vector_type(4), aligned(8)));

// ---------------------------------------------------------------------------
// K0 (512 x 64): ff[o] = 2*(0.25 + sum_m fodd[m] cos(2pi o(2m+1)/512)) * sinc.
// Direct double cos with exact integer phase mod 512 -- no tables, no LDS.
// ---------------------------------------------------------------------------
__global__ __launch_bounds__(64) void ir_spectrum(float* __restrict__ ffg) {
    const int o = blockIdx.x;
    const int t = threadIdx.x;
    double s = 0.0;
    #pragma unroll
    for (int i = 0; i < 4; ++i) {
        const int m = t + 64 * i;
        const int idx = 2 * m + 1;
        const int n = (idx < 256) ? idx : (512 - idx);
        const double fv = -1.0 / ((M_PI * n) * (M_PI * n));
        const int ph = (o * idx) & 511;
        s += fv * cos((2.0 * M_PI / 512.0) * (double)ph);
    }
    #pragma unroll
    for (int off = 32; off; off >>= 1) s += __shfl_down(s, off, 64);
    if (t == 0) {
        double ff = 0.5 + 2.0 * s;
        if (o > 0) {
            const double freq = (o <= 256) ? (double)o / 512.0 : ((double)o - 512.0) / 512.0;
            const double w = M_PI * freq;   // sinc even; fftfreq sign irrelevant
            ff *= sin(w) / w;
        }
        ffg[o] = (float)ff;
    }
}

// ---------------------------------------------------------------------------
// K1 (512 x 64): hr[o] = (1/512) sum_k ff[k] cos(2pi k o / 512).
// ---------------------------------------------------------------------------
__global__ __launch_bounds__(64) void ir_impulse(const float* __restrict__ ffg,
                                                 float* __restrict__ hr) {
    const int o = blockIdx.x;
    const int t = threadIdx.x;
    double s = 0.0;
    #pragma unroll
    for (int i = 0; i < 8; ++i) {
        const int k = t + 64 * i;
        const int ph = (o * k) & 511;
        s += (double)ffg[k] * cos((2.0 * M_PI / 512.0) * (double)ph);
    }
    #pragma unroll
    for (int off = 32; off; off >>= 1) s += __shfl_down(s, off, 64);
    if (t == 0) hr[o] = (float)(s / 512.0);
}

// ---------------------------------------------------------------------------
// K2: circular conv, filtered[n] = sum_j hr[j] * row[(n-j) mod 512].
// Block = (angle a, batch-pair p): rows of batches 2p and 2p+1 at angle a.
// hr read from GLOBAL at wave-uniform J -> s_load (no LDS pipe, no conflicts).
// Output written pair-INTERLEAVED: fil2row[16 + 2n + r] = batch(2p+r)[n].
// ---------------------------------------------------------------------------
__global__ __launch_bounds__(256) void ir_filter(const float* __restrict__ sino,
                                                 const float* __restrict__ hr,
                                                 float* __restrict__ fil2) {
    __shared__ float row2[2][2 * P];
    const int a = blockIdx.x;
    const int p = blockIdx.y;
    const int t = threadIdx.x;
    const int r = t >> 7;             // batch within pair
    const int tt = t & 127;           // outputs 4tt..4tt+3
    const int b = 2 * p + r;

    const float* src = sino + ((size_t)b * NA + a) * P;
    const float4 v = *(const float4*)(src + 4 * tt);
    *(float4*)&row2[r][4 * tt] = v;
    *(float4*)&row2[r][4 * tt + P] = v;
    __syncthreads();

    float a0 = 0.f, a1 = 0.f, a2 = 0.f, a3 = 0.f;
    #pragma unroll 2
    for (int J = 0; J < P; J += 4) {
        const int base = P + 4 * tt - J;
        const float4 A  = *(const float4*)&row2[r][base];      // w[0..3]
        const float4 Bv = *(const float4*)&row2[r][base - 4];  // w[-4..-1]
        const float h0 = hr[J], h1 = hr[J + 1], h2v = hr[J + 2], h3 = hr[J + 3];
        a0 = fmaf(h0, A.x, a0); a0 = fmaf(h1, Bv.w, a0); a0 = fmaf(h2v, Bv.z, a0); a0 = fmaf(h3, Bv.y, a0);
        a1 = fmaf(h0, A.y, a1); a1 = fmaf(h1, A.x, a1); a1 = fmaf(h2v, Bv.w, a1); a1 = fmaf(h3, Bv.z, a1);
        a2 = fmaf(h0, A.z, a2); a2 = fmaf(h1, A.y, a2); a2 = fmaf(h2v, A.x, a2); a2 = fmaf(h3, Bv.w, a2);
        a3 = fmaf(h0, A.w, a3); a3 = fmaf(h1, A.z, a3); a3 = fmaf(h2v, A.y, a3); a3 = fmaf(h3, A.x, a3);
    }
    float* frow = fil2 + ((size_t)p * NA + a) * FS2;
    const int o0 = FOFF2 + 8 * tt + r;
    frow[o0]     = a0;
    frow[o0 + 2] = a1;
    frow[o0 + 4] = a2;
    frow[o0 + 6] = a3;
    if (t < FOFF2) {                  // zero pads (ws re-poisoned every call)
        frow[t] = 0.f;
        frow[FOFF2 + 2 * P + t] = 0.f;
    }
}

// ---------------------------------------------------------------------------
// K3: backprojection, batch-pair per block. 32x32 tile; per-angle 100-float
// interleaved window in LDS (p linear in (w,h) -> corner-bounded, clamp-free).
// ONE 16B LDS read at 2j serves both bilinear taps of BOTH batches.
// ---------------------------------------------------------------------------
__global__ __launch_bounds__(256) void ir_backproject(const float* __restrict__ fil2,
                                                      float* __restrict__ out) {
    __shared__ float4 angc[NA];       // (s, c, qbias = 256 - base, (float)base)
    __shared__ float win[NA * WSF];   // 72 KB

    const int t = threadIdx.x;
    const int lane = t & 63;
    const int wave = t >> 6;
    const int w0 = blockIdx.x * TS, h0 = blockIdx.y * TS;
    const int p = blockIdx.z;         // batch pair

    // thread's 4 pixels: (w,h), (w+16,h), (w,h+16), (w+16,h+16)
    const int w = w0 + (lane & 15);
    const int h = h0 + (lane >> 4) + 4 * wave;

    const int ix0 = 255 - w, ix1 = ix0 - 16;   // reversed x axis
    const int iy0 = h - 256, iy1 = iy0 + 16;
    const int r2 = 256 * 256;
    const int m00 = (ix0 * ix0 + iy0 * iy0) <= r2;
    const int m01 = (ix1 * ix1 + iy0 * iy0) <= r2;
    const int m10 = (ix0 * ix0 + iy1 * iy1) <= r2;
    const int m11 = (ix1 * ix1 + iy1 * iy1) <= r2;

    float* o0 = out + (((size_t)(2 * p) * P) + h) * P + w;   // batch 2p
    float* o1 = o0 + (size_t)P * P;                          // batch 2p+1

    if (__syncthreads_count(m00 | m01 | m10 | m11) == 0) {   // tile fully outside
        o0[0] = 0.f; o0[16] = 0.f; o0[16 * P] = 0.f; o0[16 * P + 16] = 0.f;
        o1[0] = 0.f; o1[16] = 0.f; o1[16 * P] = 0.f; o1[16 * P + 16] = 0.f;
        return;
    }

    // Phase A: per-angle constants; even window base from tile-corner bounds
    if (t < NA) {
        const float th = (float)t * (float)(M_PI / (double)(NA - 1));
        const float s = sinf(th), c = cosf(th);           // s >= 0 on [0,pi]
        const float xlo = (float)(224 - w0);              // min x over tile
        const float ylo = (float)(h0 - 256), yhi = (float)(h0 - 225);
        const float pmin = s * xlo + fminf(c * ylo, c * yhi) + 256.0f;
        const int base = ((int)floorf(pmin) - 2) & ~1;    // even, fp-slop safety
        angc[t] = make_float4(s, c, (float)(256 - base), (float)base);
    }
    __syncthreads();

    // Phase B: stage interleaved windows (16B-aligned global & LDS accesses)
    const float* fbase = fil2 + (size_t)p * NA * FS2;
    for (int idx = t; idx < NA * (WSF / 4); idx += 256) {
        const int a = idx / (WSF / 4);
        const int i = idx - a * (WSF / 4);
        const int base = (int)angc[a].w;
        const f4g vv = *(const f4g*)(fbase + a * FS2 + FOFF2 + 2 * base + 4 * i);
        *(f4g*)(win + a * WSF + 4 * i) = vv;
    }
    __syncthreads();

    // Phase C: q = p - base in [~2, 49); j = trunc(q); window float4 at 2j =
    // (b0[j], b1[j], b0[j+1], b1[j+1]) -> both taps, both batches, one read.
    const float xf = (float)ix0;
    const float yf = (float)iy0;
    float a00 = 0.f, a01 = 0.f, a10 = 0.f, a11 = 0.f;   // batch 2p
    float b00 = 0.f, b01 = 0.f, b10 = 0.f, b11 = 0.f;   // batch 2p+1
    #pragma unroll 2
    for (int a = 0; a < NA; ++a) {
        const float4 ac = angc[a];
        const float q00 = fmaf(xf, ac.x, fmaf(yf, ac.y, ac.z));
        const float q01 = fmaf(-16.f, ac.x, q00);
        const float q10 = fmaf( 16.f, ac.y, q00);
        const float q11 = fmaf( 16.f, ac.y, q01);
        const float* wb = win + a * WSF;
        {
            const int j = (int)q00; const float fr = FRACT(q00);
            const f4l W = *(const f4l*)(wb + 2 * j);
            a00 = fmaf(1.f - fr, W.x, fmaf(fr, W.z, a00));
            b00 = fmaf(1.f - fr, W.y, fmaf(fr, W.w, b00));
        }
        {
            const int j = (int)q01; const float fr = FRACT(q01);
            const f4l W = *(const f4l*)(wb + 2 * j);
            a01 = fmaf(1.f - fr, W.x, fmaf(fr, W.z, a01));
            b01 = fmaf(1.f - fr, W.y, fmaf(fr, W.w, b01));
        }
        {
            const int j = (int)q10; const float fr = FRACT(q10);
            const f4l W = *(const f4l*)(wb + 2 * j);
            a10 = fmaf(1.f - fr, W.x, fmaf(fr, W.z, a10));
            b10 = fmaf(1.f - fr, W.y, fmaf(fr, W.w, b10));
        }
        {
            const int j = (int)q11; const float fr = FRACT(q11);
            const f4l W = *(const f4l*)(wb + 2 * j);
            a11 = fmaf(1.f - fr, W.x, fmaf(fr, W.z, a11));
            b11 = fmaf(1.f - fr, W.y, fmaf(fr, W.w, b11));
        }
    }

    const float scale = (float)(M_PI / (2.0 * NA));
    o0[0]           = m00 ? a00 * scale : 0.f;
    o0[16]          = m01 ? a01 * scale : 0.f;
    o0[16 * P]      = m10 ? a10 * scale : 0.f;
    o0[16 * P + 16] = m11 ? a11 * scale : 0.f;
    o1[0]           = m00 ? b00 * scale : 0.f;
    o1[16]          = m01 ? b01 * scale : 0.f;
    o1[16 * P]      = m10 ? b10 * scale : 0.f;
    o1[16 * P + 16] = m11 ? b11 * scale : 0.f;
}

// ---------------------------------------------------------------------------
extern "C" void kernel_launch(void* const* d_in, const int* in_sizes, int n_in,
                              void* d_out, int out_size, void* d_ws, size_t ws_size,
                              hipStream_t stream) {
    const float* sino = (const float*)d_in[0];
    float* out = (float*)d_out;
    float* ws = (float*)d_ws;

    float* ffg  = ws;                      // 512
    float* hr   = ws + 512;                // 512
    float* fil2 = ws + 1024 + GUARD;       // 360 * 1056 = 380160 floats (+guards)

    ir_spectrum<<<P, 64, 0, stream>>>(ffg);
    ir_impulse<<<P, 64, 0, stream>>>(ffg, hr);

    dim3 gridF(NA, NB / 2);
    ir_filter<<<gridF, 256, 0, stream>>>(sino, hr, fil2);

    dim3 gridB(P / TS, P / TS, NB / 2);
    ir_backproject<<<gridB, 256, 0, stream>>>(fil2, out);
}

// Round 6
// 115.138 us; speedup vs baseline: 1.6500x; 1.0523x over previous
//
#include <hip/hip_runtime.h>
#include <math.h>

#define P      512
#define NA     180
#define NB     4
#define FS2    1056    // interleaved pair row: 16 zero + 1024 data + 16 zero floats
#define FOFF2  16
#define GUARD  512     // float guard before/after fil2 for window-staging overreach
#define TS     32      // backprojection pixel tile
#define WSF    100     // window floats per angle (50 positions x 2 batches)
#define AHALF  90      // angles staged per LDS round

#if __has_builtin(__builtin_amdgcn_fractf)
#define FRACT(x) __builtin_amdgcn_fractf(x)
#else
#define FRACT(x) ((x) - floorf(x))
#endif

typedef float f4g __attribute__((ext_vector_type(4), aligned(16)));
typedef float f4l __attribute__((ext_vector_type(4), aligned(8)));

// ---------------------------------------------------------------------------
// K0 (512 x 64): ff[o] = 2*(0.25 + sum_m fodd[m] cos(2pi o(2m+1)/512)) * sinc.
// Direct double cos with exact integer phase mod 512 -- no tables, no LDS.
// ---------------------------------------------------------------------------
__global__ __launch_bounds__(64) void ir_spectrum(float* __restrict__ ffg) {
    const int o = blockIdx.x;
    const int t = threadIdx.x;
    double s = 0.0;
    #pragma unroll
    for (int i = 0; i < 4; ++i) {
        const int m = t + 64 * i;
        const int idx = 2 * m + 1;
        const int n = (idx < 256) ? idx : (512 - idx);
        const double fv = -1.0 / ((M_PI * n) * (M_PI * n));
        const int ph = (o * idx) & 511;
        s += fv * cos((2.0 * M_PI / 512.0) * (double)ph);
    }
    #pragma unroll
    for (int off = 32; off; off >>= 1) s += __shfl_down(s, off, 64);
    if (t == 0) {
        double ff = 0.5 + 2.0 * s;
        if (o > 0) {
            const double freq = (o <= 256) ? (double)o / 512.0 : ((double)o - 512.0) / 512.0;
            const double w = M_PI * freq;   // sinc even; fftfreq sign irrelevant
            ff *= sin(w) / w;
        }
        ffg[o] = (float)ff;
    }
}

// ---------------------------------------------------------------------------
// K1 (512 x 64): hr[o] = (1/512) sum_k ff[k] cos(2pi k o / 512).
// ---------------------------------------------------------------------------
__global__ __launch_bounds__(64) void ir_impulse(const float* __restrict__ ffg,
                                                 float* __restrict__ hr) {
    const int o = blockIdx.x;
    const int t = threadIdx.x;
    double s = 0.0;
    #pragma unroll
    for (int i = 0; i < 8; ++i) {
        const int k = t + 64 * i;
        const int ph = (o * k) & 511;
        s += (double)ffg[k] * cos((2.0 * M_PI / 512.0) * (double)ph);
    }
    #pragma unroll
    for (int off = 32; off; off >>= 1) s += __shfl_down(s, off, 64);
    if (t == 0) hr[o] = (float)(s / 512.0);
}

// ---------------------------------------------------------------------------
// K2: circular conv, filtered[n] = sum_j hr[j] * row[(n-j) mod 512].
// Block = (angle a, batch-pair p). hr read at wave-uniform J -> s_load.
// Rolling register window: A(J+4) == Bv(J), so ONE ds_read_b128 per K-step.
// Output pair-INTERLEAVED: fil2row[16 + 2n + r] = batch(2p+r)[n].
// ---------------------------------------------------------------------------
__global__ __launch_bounds__(256) void ir_filter(const float* __restrict__ sino,
                                                 const float* __restrict__ hr,
                                                 float* __restrict__ fil2) {
    __shared__ float row2[2][2 * P];
    const int a = blockIdx.x;
    const int p = blockIdx.y;
    const int t = threadIdx.x;
    const int r = t >> 7;             // batch within pair
    const int tt = t & 127;           // outputs 4tt..4tt+3
    const int b = 2 * p + r;

    const float* src = sino + ((size_t)b * NA + a) * P;
    const float4 v = *(const float4*)(src + 4 * tt);
    *(float4*)&row2[r][4 * tt] = v;
    *(float4*)&row2[r][4 * tt + P] = v;
    __syncthreads();

    const int base0 = P + 4 * tt;
    float4 A = *(const float4*)&row2[r][base0];    // window floats w[0..3]
    float a0 = 0.f, a1 = 0.f, a2 = 0.f, a3 = 0.f;
    #pragma unroll 4
    for (int J = 0; J < P; J += 4) {
        const float4 Bv = *(const float4*)&row2[r][base0 - J - 4];  // w[-4..-1]
        const float h0 = hr[J], h1 = hr[J + 1], h2v = hr[J + 2], h3 = hr[J + 3];
        a0 = fmaf(h0, A.x, a0); a0 = fmaf(h1, Bv.w, a0); a0 = fmaf(h2v, Bv.z, a0); a0 = fmaf(h3, Bv.y, a0);
        a1 = fmaf(h0, A.y, a1); a1 = fmaf(h1, A.x, a1); a1 = fmaf(h2v, Bv.w, a1); a1 = fmaf(h3, Bv.z, a1);
        a2 = fmaf(h0, A.z, a2); a2 = fmaf(h1, A.y, a2); a2 = fmaf(h2v, A.x, a2); a2 = fmaf(h3, Bv.w, a2);
        a3 = fmaf(h0, A.w, a3); a3 = fmaf(h1, A.z, a3); a3 = fmaf(h2v, A.y, a3); a3 = fmaf(h3, A.x, a3);
        A = Bv;                                    // slide the register window
    }
    float* frow = fil2 + ((size_t)p * NA + a) * FS2;
    const int o0 = FOFF2 + 8 * tt + r;
    frow[o0]     = a0;
    frow[o0 + 2] = a1;
    frow[o0 + 4] = a2;
    frow[o0 + 6] = a3;
    if (t < FOFF2) {                  // zero pads (ws re-poisoned every call)
        frow[t] = 0.f;
        frow[FOFF2 + 2 * P + t] = 0.f;
    }
}

// ---------------------------------------------------------------------------
// K3: backprojection, batch-pair per block, 32x32 tile. Angle-SPLIT windows:
// stage 90 angles (36 KB) -> compute -> restage next 90. ~39 KB LDS total ->
// 4 blocks/CU (vs 2 with all 180), doubling latency-hiding waves.
// One 16B LDS read at 2j serves both bilinear taps of BOTH batches.
// ---------------------------------------------------------------------------
__global__ __launch_bounds__(256) void ir_backproject(const float* __restrict__ fil2,
                                                      float* __restrict__ out) {
    __shared__ float4 angc[NA];          // (s, c, qbias = 256 - base, (float)base)
    __shared__ float win[AHALF * WSF];   // 36 KB, reused per angle half

    const int t = threadIdx.x;
    const int lane = t & 63;
    const int wave = t >> 6;
    const int w0 = blockIdx.x * TS, h0 = blockIdx.y * TS;
    const int p = blockIdx.z;            // batch pair

    // thread's 4 pixels: (w,h), (w+16,h), (w,h+16), (w+16,h+16)
    const int w = w0 + (lane & 15);
    const int h = h0 + (lane >> 4) + 4 * wave;

    const int ix0 = 255 - w, ix1 = ix0 - 16;   // reversed x axis
    const int iy0 = h - 256, iy1 = iy0 + 16;
    const int r2 = 256 * 256;
    const int m00 = (ix0 * ix0 + iy0 * iy0) <= r2;
    const int m01 = (ix1 * ix1 + iy0 * iy0) <= r2;
    const int m10 = (ix0 * ix0 + iy1 * iy1) <= r2;
    const int m11 = (ix1 * ix1 + iy1 * iy1) <= r2;

    float* o0 = out + (((size_t)(2 * p) * P) + h) * P + w;   // batch 2p
    float* o1 = o0 + (size_t)P * P;                          // batch 2p+1

    if (__syncthreads_count(m00 | m01 | m10 | m11) == 0) {   // tile fully outside
        o0[0] = 0.f; o0[16] = 0.f; o0[16 * P] = 0.f; o0[16 * P + 16] = 0.f;
        o1[0] = 0.f; o1[16] = 0.f; o1[16 * P] = 0.f; o1[16 * P + 16] = 0.f;
        return;
    }

    // Phase A: per-angle constants; even window base from tile-corner bounds
    if (t < NA) {
        const float th = (float)t * (float)(M_PI / (double)(NA - 1));
        const float s = sinf(th), c = cosf(th);           // s >= 0 on [0,pi]
        const float xlo = (float)(224 - w0);              // min x over tile
        const float ylo = (float)(h0 - 256), yhi = (float)(h0 - 225);
        const float pmin = s * xlo + fminf(c * ylo, c * yhi) + 256.0f;
        const int base = ((int)floorf(pmin) - 2) & ~1;    // even, fp-slop safety
        angc[t] = make_float4(s, c, (float)(256 - base), (float)base);
    }
    __syncthreads();

    const float xf = (float)ix0;
    const float yf = (float)iy0;
    const float* fbase = fil2 + (size_t)p * NA * FS2;
    float a00 = 0.f, a01 = 0.f, a10 = 0.f, a11 = 0.f;   // batch 2p
    float b00 = 0.f, b01 = 0.f, b10 = 0.f, b11 = 0.f;   // batch 2p+1

    #pragma unroll
    for (int half = 0; half < 2; ++half) {
        const int A0 = half * AHALF;

        // Phase B: stage this half's interleaved windows (16B-aligned)
        for (int idx = t; idx < AHALF * (WSF / 4); idx += 256) {
            const int al = idx / (WSF / 4);
            const int i = idx - al * (WSF / 4);
            const int a = A0 + al;
            const int base = (int)angc[a].w;
            const f4g vv = *(const f4g*)(fbase + a * FS2 + FOFF2 + 2 * base + 4 * i);
            *(f4g*)(win + al * WSF + 4 * i) = vv;
        }
        __syncthreads();

        // Phase C: q = p - base in [~2, 49); j = trunc(q); float4 at 2j =
        // (b0[j], b1[j], b0[j+1], b1[j+1]) -> both taps, both batches, 1 read.
        #pragma unroll 2
        for (int al = 0; al < AHALF; ++al) {
            const float4 ac = angc[A0 + al];
            const float q00 = fmaf(xf, ac.x, fmaf(yf, ac.y, ac.z));
            const float q01 = fmaf(-16.f, ac.x, q00);
            const float q10 = fmaf( 16.f, ac.y, q00);
            const float q11 = fmaf( 16.f, ac.y, q01);
            const float* wb = win + al * WSF;
            {
                const int j = (int)q00; const float fr = FRACT(q00);
                const f4l W = *(const f4l*)(wb + 2 * j);
                a00 = fmaf(1.f - fr, W.x, fmaf(fr, W.z, a00));
                b00 = fmaf(1.f - fr, W.y, fmaf(fr, W.w, b00));
            }
            {
                const int j = (int)q01; const float fr = FRACT(q01);
                const f4l W = *(const f4l*)(wb + 2 * j);
                a01 = fmaf(1.f - fr, W.x, fmaf(fr, W.z, a01));
                b01 = fmaf(1.f - fr, W.y, fmaf(fr, W.w, b01));
            }
            {
                const int j = (int)q10; const float fr = FRACT(q10);
                const f4l W = *(const f4l*)(wb + 2 * j);
                a10 = fmaf(1.f - fr, W.x, fmaf(fr, W.z, a10));
                b10 = fmaf(1.f - fr, W.y, fmaf(fr, W.w, b10));
            }
            {
                const int j = (int)q11; const float fr = FRACT(q11);
                const f4l W = *(const f4l*)(wb + 2 * j);
                a11 = fmaf(1.f - fr, W.x, fmaf(fr, W.z, a11));
                b11 = fmaf(1.f - fr, W.y, fmaf(fr, W.w, b11));
            }
        }
        if (half == 0) __syncthreads();   // protect win before restage (uniform)
    }

    const float scale = (float)(M_PI / (2.0 * NA));
    o0[0]           = m00 ? a00 * scale : 0.f;
    o0[16]          = m01 ? a01 * scale : 0.f;
    o0[16 * P]      = m10 ? a10 * scale : 0.f;
    o0[16 * P + 16] = m11 ? a11 * scale : 0.f;
    o1[0]           = m00 ? b00 * scale : 0.f;
    o1[16]          = m01 ? b01 * scale : 0.f;
    o1[16 * P]      = m10 ? b10 * scale : 0.f;
    o1[16 * P + 16] = m11 ? b11 * scale : 0.f;
}

// ---------------------------------------------------------------------------
extern "C" void kernel_launch(void* const* d_in, const int* in_sizes, int n_in,
                              void* d_out, int out_size, void* d_ws, size_t ws_size,
                              hipStream_t stream) {
    const float* sino = (const float*)d_in[0];
    float* out = (float*)d_out;
    float* ws = (float*)d_ws;

    float* ffg  = ws;                      // 512
    float* hr   = ws + 512;                // 512
    float* fil2 = ws + 1024 + GUARD;       // 360 * 1056 = 380160 floats (+guards)

    ir_spectrum<<<P, 64, 0, stream>>>(ffg);
    ir_impulse<<<P, 64, 0, stream>>>(ffg, hr);

    dim3 gridF(NA, NB / 2);
    ir_filter<<<gridF, 256, 0, stream>>>(sino, hr, fil2);

    dim3 gridB(P / TS, P / TS, NB / 2);
    ir_backproject<<<gridB, 256, 0, stream>>>(fil2, out);
}